// Round 6
// baseline (261.305 us; speedup 1.0000x reference)
//
#include <hip/hip_runtime.h>
#include <hip/hip_bf16.h>

// LINK forward: out[i, o] = b[o] + sum over edges (i -> j) of W[o, j]
// N=100000, OUT=64, E=3200000.
//
// R6: setup was ~158us vs 61us gather. Root cause: scatter at 1563 frontiers
// x 2.6 edges/block = 10.5B partial-line writes + 9.8MB count-matrix traffic.
// Replace with two-level radix, dense frontiers, no matrices:
//   fine_count: LDS hist(1563) + global atomic flush      (rows read 1x)
//   scan_init : 1 block scans 1563 -> base_g, cursors
//   P1: partition into 196 super-buckets (512 rows): 84B/frontier/block,
//       range reservation via 1 global atomicAdd per (block,sb)
//   P2: per-sb refine into 8 fine buckets: 2KB/frontier, wave-ballot ranking
//   sort_gather: unchanged from R5 (bf16 WT, half-wave/edge, f32 accum)

#define OUTC 64
#define FSHIFT 6           // 64 rows per fine bucket
#define SBSHIFT 9          // 512 rows per super-bucket (8 fine)
#define NF_MAX 2048
#define CHUNK 4096         // edges per chunk WG (count + P1)
#define P2CHUNK 4096       // edges per P2 block
#define MAXJ 5             // max P2 blocks per sb (capacity 20480 >> 16384+32sig)
#define CAP 2560           // per-fine-bucket LDS col capacity (mean 2048)

__device__ inline unsigned f2bf(float x) {           // RNE f32 -> bf16 bits
    unsigned u = __float_as_uint(x);
    return (u + 0x7FFFu + ((u >> 16) & 1u)) >> 16;
}
__device__ inline float bf_lo(unsigned u) { return __uint_as_float(u << 16); }
__device__ inline float bf_hi(unsigned u) { return __uint_as_float(u & 0xFFFF0000u); }

// ---------------- A: transpose W[64][N] -> WTh[N][32] packed bf16x2 ----------------
__global__ __launch_bounds__(256) void transpose_cast(const float* __restrict__ W,
                                                      unsigned* __restrict__ WTh, int n) {
    __shared__ float tile[64][65];
    const int n0   = blockIdx.x * 64;
    const int lane = threadIdx.x & 63;
    const int wv   = threadIdx.x >> 6;
    #pragma unroll
    for (int k = 0; k < 16; ++k) {
        int o  = wv * 16 + k;
        int nn = n0 + lane;
        tile[o][lane] = (nn < n) ? W[(size_t)o * n + nn] : 0.f;
    }
    __syncthreads();
    const int u   = threadIdx.x & 31;
    const int nbs = threadIdx.x >> 5;
    #pragma unroll
    for (int k = 0; k < 8; ++k) {
        int nl = nbs + 8 * k;
        int nn = n0 + nl;
        if (nn < n)
            WTh[(size_t)nn * 32 + u] = f2bf(tile[2 * u][nl]) | (f2bf(tile[2 * u + 1][nl]) << 16);
    }
}

// ---------------- B: fine-bucket counts (LDS hist + atomic flush) ----------------
__global__ __launch_bounds__(256) void fine_count(const int* __restrict__ rows,
                                                  int* __restrict__ bcnt,
                                                  int E, int NF) {
    __shared__ int h[NF_MAX];
    const int tid = threadIdx.x;
    for (int i = tid; i < NF; i += 256) h[i] = 0;
    __syncthreads();
    const int base = blockIdx.x * CHUNK;
    const int lim  = min(E, base + CHUNK);
    #pragma unroll
    for (int it = 0; it < CHUNK / 1024; ++it) {
        int e = base + it * 1024 + tid * 4;
        if (e + 3 < lim) {
            int4 r = *(const int4*)(rows + e);
            atomicAdd(&h[r.x >> FSHIFT], 1);
            atomicAdd(&h[r.y >> FSHIFT], 1);
            atomicAdd(&h[r.z >> FSHIFT], 1);
            atomicAdd(&h[r.w >> FSHIFT], 1);
        } else {
            for (int j = 0; j < 4; ++j)
                if (e + j < lim) atomicAdd(&h[rows[e + j] >> FSHIFT], 1);
        }
    }
    __syncthreads();
    for (int i = tid; i < NF; i += 256) {
        int c = h[i];
        if (c) atomicAdd(&bcnt[i], c);
    }
}

// ---------------- C: scan fine counts -> base_g; init cursors ----------------
__global__ __launch_bounds__(512) void scan_init(const int* __restrict__ bcnt,
                                                 int* __restrict__ base_g,
                                                 int* __restrict__ fcur,
                                                 int* __restrict__ sbcur,
                                                 int NF, int NSB, int E) {
    __shared__ int lds[512];
    const int tid  = threadIdx.x;
    const int base = tid * 4;
    int v[4];
    int s = 0;
    #pragma unroll
    for (int k = 0; k < 4; ++k) {
        v[k] = (base + k < NF) ? bcnt[base + k] : 0;
        s += v[k];
    }
    lds[tid] = s;
    __syncthreads();
    for (int off = 1; off < 512; off <<= 1) {
        int t = 0;
        if (tid >= off) t = lds[tid - off];
        __syncthreads();
        if (tid >= off) lds[tid] += t;
        __syncthreads();
    }
    int ex = lds[tid] - s;
    #pragma unroll
    for (int k = 0; k < 4; ++k) {
        if (base + k < NF) { base_g[base + k] = ex; fcur[base + k] = ex; }
        ex += v[k];
    }
    __syncthreads();
    if (tid == 0) base_g[NF] = E;
    __syncthreads();
    for (int sb = tid; sb < NSB; sb += 512) sbcur[sb] = base_g[sb * 8];
}

// ---------------- D: P1 scatter into 196 super-buckets ----------------
__global__ __launch_bounds__(256) void scatter_sb(const int* __restrict__ rows,
                                                  const int* __restrict__ cols,
                                                  int* __restrict__ sbcur,
                                                  unsigned* __restrict__ packed1,
                                                  int E, int NSB) {
    __shared__ int h[256];
    __shared__ int cur[256];
    const int tid = threadIdx.x;
    if (tid < NSB) h[tid] = 0;
    __syncthreads();
    const int base = blockIdx.x * CHUNK;
    const int lim  = min(E, base + CHUNK);
    // pass A: count (chunk stays L1-resident for pass B)
    #pragma unroll
    for (int it = 0; it < CHUNK / 1024; ++it) {
        int e = base + it * 1024 + tid * 4;
        if (e + 3 < lim) {
            int4 r = *(const int4*)(rows + e);
            atomicAdd(&h[r.x >> SBSHIFT], 1);
            atomicAdd(&h[r.y >> SBSHIFT], 1);
            atomicAdd(&h[r.z >> SBSHIFT], 1);
            atomicAdd(&h[r.w >> SBSHIFT], 1);
        } else {
            for (int j = 0; j < 4; ++j)
                if (e + j < lim) atomicAdd(&h[rows[e + j] >> SBSHIFT], 1);
        }
    }
    __syncthreads();
    // reserve contiguous range per super-bucket
    if (tid < NSB) {
        int c = h[tid];
        cur[tid] = c ? atomicAdd(&sbcur[tid], c) : 0;
    }
    __syncthreads();
    // pass B: scatter packed (row&511)<<17 | col
    #pragma unroll
    for (int it = 0; it < CHUNK / 1024; ++it) {
        int e = base + it * 1024 + tid * 4;
        if (e + 3 < lim) {
            int4 r = *(const int4*)(rows + e);
            int4 cc = *(const int4*)(cols + e);
            int p0 = atomicAdd(&cur[r.x >> SBSHIFT], 1);
            int p1 = atomicAdd(&cur[r.y >> SBSHIFT], 1);
            int p2 = atomicAdd(&cur[r.z >> SBSHIFT], 1);
            int p3 = atomicAdd(&cur[r.w >> SBSHIFT], 1);
            packed1[p0] = ((unsigned)(r.x & 511) << 17) | (unsigned)cc.x;
            packed1[p1] = ((unsigned)(r.y & 511) << 17) | (unsigned)cc.y;
            packed1[p2] = ((unsigned)(r.z & 511) << 17) | (unsigned)cc.z;
            packed1[p3] = ((unsigned)(r.w & 511) << 17) | (unsigned)cc.w;
        } else {
            for (int j = 0; j < 4; ++j) {
                if (e + j < lim) {
                    int r = rows[e + j];
                    int p = atomicAdd(&cur[r >> SBSHIFT], 1);
                    packed1[p] = ((unsigned)(r & 511) << 17) | (unsigned)cols[e + j];
                }
            }
        }
    }
}

// ---------------- E: P2 refine each super-bucket into its 8 fine buckets ----------------
__global__ __launch_bounds__(256) void scatter_fine(const unsigned* __restrict__ packed1,
                                                    const int* __restrict__ base_g,
                                                    int* __restrict__ fcur,
                                                    unsigned* __restrict__ packed2,
                                                    int NF, int E) {
    const int s    = blockIdx.x;
    const int j    = blockIdx.y;
    const int f0   = s * 8;
    const int fend = min(f0 + 8, NF);
    const int rs   = base_g[f0];
    const int re   = base_g[fend];
    const int start = rs + j * P2CHUNK;
    if (start >= re) return;
    const int lim  = min(re, start + P2CHUNK);
    __shared__ int cur[8];
    __shared__ int hh[8];
    const int tid  = threadIdx.x;
    const int lane = tid & 63;
    if (tid < 8) hh[tid] = 0;
    __syncthreads();
    // count via per-wave ballots (no hot LDS atomics)
    for (int e = start + tid; e < lim + (lane ? 0 : 0); e += 256) { }
    for (int eb = start + (tid & ~63); eb < lim; eb += 256) {
        int e = eb + lane;
        bool act = (e < lim);
        int key = act ? (int)((packed1[e] >> 17) >> 6) : 8;
        #pragma unroll
        for (int k = 0; k < 8; ++k) {
            unsigned long long m = __ballot(key == k);
            if (lane == (unsigned)k && m) atomicAdd(&hh[k], __popcll(m));
        }
    }
    __syncthreads();
    if (tid < 8) {
        int c = hh[tid];
        cur[tid] = c ? atomicAdd(&fcur[f0 + tid], c) : 0;
    }
    __syncthreads();
    // scatter via per-wave ballot ranking
    for (int eb = start + (tid & ~63); eb < lim; eb += 256) {
        int e = eb + lane;
        bool act = (e < lim);
        unsigned u = act ? packed1[e] : 0u;
        int rrel = (int)(u >> 17);
        int key  = act ? (rrel >> 6) : 8;
        #pragma unroll
        for (int k = 0; k < 8; ++k) {
            unsigned long long m = __ballot(key == k);
            if (m) {
                int leader = __ffsll((unsigned long long)m) - 1;
                int cnt    = __popcll(m);
                int bs = 0;
                if (lane == (unsigned)leader && key == k)
                    bs = atomicAdd(&cur[k], cnt);
                bs = __shfl(bs, leader);
                if (key == k) {
                    int rank = __popcll(m & ((1ull << lane) - 1ull));
                    packed2[bs + rank] = ((unsigned)(rrel & 63) << 17) | (u & 0x1FFFFu);
                }
            }
        }
    }
}

// ---------------- F: fused per-fine-bucket LDS counting sort + gather ----------------
__global__ __launch_bounds__(256) void sort_gather(const unsigned* __restrict__ WTh,
                                                   const unsigned* __restrict__ packed,
                                                   const int* __restrict__ base_g,
                                                   const float* __restrict__ bias,
                                                   float* __restrict__ out, int N) {
    __shared__ unsigned scol[CAP];            // 10 KB
    __shared__ int cnt[64], off0[64], tend[64], cur[64];
    __shared__ int ovf_n;
    __shared__ unsigned ovf[128];
    const int b    = blockIdx.x;
    const int tid  = threadIdx.x;
    const int lane = tid & 63;
    const int w    = tid >> 6;
    const int start = base_g[b];
    const int size  = base_g[b + 1] - start;
    if (tid < 64) cnt[tid] = 0;
    if (tid == 0) ovf_n = 0;
    __syncthreads();
    for (int e = tid; e < size; e += 256)
        atomicAdd(&cnt[packed[start + e] >> 17], 1);
    __syncthreads();
    int v = (tid < 64) ? cnt[tid] : 0;
    for (int off = 1; off < 64; off <<= 1) {
        int t = 0;
        if (tid < 64 && tid >= off) t = cnt[tid - off];
        __syncthreads();
        if (tid < 64 && tid >= off) cnt[tid] += t;
        __syncthreads();
    }
    if (tid < 64) { tend[tid] = cnt[tid]; off0[tid] = cnt[tid] - v; cur[tid] = cnt[tid] - v; }
    __syncthreads();
    for (int e = tid; e < size; e += 256) {
        unsigned u = packed[start + e];
        int p = atomicAdd(&cur[u >> 17], 1);
        if (p < CAP) scol[p] = u & 0x1FFFFu;
        else { int oi = atomicAdd(&ovf_n, 1); if (oi < 128) ovf[oi] = u; }
    }
    __syncthreads();
    const int hl   = lane & 31;
    const int half = lane >> 5;
    const float bx = bias[2 * hl];
    const float by = bias[2 * hl + 1];
    for (int r = w; r < 64; r += 4) {
        const int n = b * 64 + r;
        if (n >= N) break;
        int s = off0[r], t = tend[r];
        if (s > CAP) s = CAP;
        if (t > CAP) t = CAP;
        float ax = 0.f, ay = 0.f;
        int e = s + half;
        for (; e + 14 < t; e += 16) {
            unsigned c0 = scol[e + 0],  c1 = scol[e + 2],  c2 = scol[e + 4],  c3 = scol[e + 6];
            unsigned c4 = scol[e + 8],  c5 = scol[e + 10], c6 = scol[e + 12], c7 = scol[e + 14];
            unsigned u0 = WTh[(size_t)c0 * 32 + hl];
            unsigned u1 = WTh[(size_t)c1 * 32 + hl];
            unsigned u2 = WTh[(size_t)c2 * 32 + hl];
            unsigned u3 = WTh[(size_t)c3 * 32 + hl];
            unsigned u4 = WTh[(size_t)c4 * 32 + hl];
            unsigned u5 = WTh[(size_t)c5 * 32 + hl];
            unsigned u6 = WTh[(size_t)c6 * 32 + hl];
            unsigned u7 = WTh[(size_t)c7 * 32 + hl];
            ax += bf_lo(u0); ay += bf_hi(u0);
            ax += bf_lo(u1); ay += bf_hi(u1);
            ax += bf_lo(u2); ay += bf_hi(u2);
            ax += bf_lo(u3); ay += bf_hi(u3);
            ax += bf_lo(u4); ay += bf_hi(u4);
            ax += bf_lo(u5); ay += bf_hi(u5);
            ax += bf_lo(u6); ay += bf_hi(u6);
            ax += bf_lo(u7); ay += bf_hi(u7);
        }
        for (; e < t; e += 2) {
            unsigned u = WTh[(size_t)scol[e] * 32 + hl];
            ax += bf_lo(u); ay += bf_hi(u);
        }
        ax += __shfl_xor(ax, 32);
        ay += __shfl_xor(ay, 32);
        if (half == 0) {
            float2 o;
            o.x = ax + bx;
            o.y = ay + by;
            ((float2*)out)[(size_t)n * 32 + hl] = o;
        }
    }
    __syncthreads();
    int no = ovf_n;
    if (no > 0) {
        if (no > 128) no = 128;
        for (int i = w; i < no; i += 4) {
            unsigned u = ovf[i];
            int n = b * 64 + (int)(u >> 17);
            if (n < N && half == 0) {
                unsigned uu = WTh[(size_t)(u & 0x1FFFFu) * 32 + hl];
                atomicAdd(&out[(size_t)n * 64 + 2 * hl],     bf_lo(uu));
                atomicAdd(&out[(size_t)n * 64 + 2 * hl + 1], bf_hi(uu));
            }
        }
    }
}

extern "C" void kernel_launch(void* const* d_in, const int* in_sizes, int n_in,
                              void* d_out, int out_size, void* d_ws, size_t ws_size,
                              hipStream_t stream) {
    const int*   edges = (const int*)d_in[0];    // [2, E]: rows then cols
    const float* W     = (const float*)d_in[1];  // [64, N]
    const float* bias  = (const float*)d_in[2];  // [64]
    float*       out   = (float*)d_out;          // [N, 64]

    const int E   = in_sizes[0] / 2;
    const int N   = in_sizes[1] / OUTC;
    const int NF  = (N + 63) / 64;               // 1563 fine buckets
    const int NSB = (NF + 7) / 8;                // 196 super-buckets

    // workspace layout (~38.5 MB)
    char* ws = (char*)d_ws;
    size_t off = 0;
    unsigned* WTh = (unsigned*)(ws + off); off += (size_t)N * 32 * sizeof(unsigned);
    off = (off + 255) & ~(size_t)255;
    int* bcnt = (int*)(ws + off);          off += (size_t)NF * sizeof(int);
    off = (off + 255) & ~(size_t)255;
    int* base_g = (int*)(ws + off);        off += (size_t)(NF + 1) * sizeof(int);
    off = (off + 255) & ~(size_t)255;
    int* fcur = (int*)(ws + off);          off += (size_t)NF * sizeof(int);
    off = (off + 255) & ~(size_t)255;
    int* sbcur = (int*)(ws + off);         off += (size_t)NSB * sizeof(int);
    off = (off + 255) & ~(size_t)255;
    unsigned* packed1 = (unsigned*)(ws + off); off += (size_t)E * sizeof(unsigned);
    off = (off + 255) & ~(size_t)255;
    unsigned* packed2 = (unsigned*)(ws + off); off += (size_t)E * sizeof(unsigned);
    (void)ws_size;

    const int* rows = edges;
    const int* cols = edges + E;

    hipMemsetAsync(bcnt, 0, (size_t)NF * sizeof(int), stream);

    transpose_cast<<<(N + 63) / 64, 256, 0, stream>>>(W, WTh, N);
    const int nchunks = (E + CHUNK - 1) / CHUNK;       // 782
    fine_count<<<nchunks, 256, 0, stream>>>(rows, bcnt, E, NF);
    scan_init<<<1, 512, 0, stream>>>(bcnt, base_g, fcur, sbcur, NF, NSB, E);
    scatter_sb<<<nchunks, 256, 0, stream>>>(rows, cols, sbcur, packed1, E, NSB);
    scatter_fine<<<dim3(NSB, MAXJ), 256, 0, stream>>>(packed1, base_g, fcur, packed2, NF, E);
    sort_gather<<<NF, 256, 0, stream>>>(WTh, packed2, base_g, bias, out, N);
}

// Round 7
// 209.676 us; speedup vs baseline: 1.2462x; 1.2462x over previous
//
#include <hip/hip_runtime.h>
#include <hip/hip_bf16.h>

// LINK forward: out[i, o] = b[o] + sum over edges (i -> j) of W[o, j]
// N=100000, OUT=64, E=3200000.
//
// R7: collapse setup to ONE partition kernel using fixed per-bucket slabs
// (capacity 2560 = mean 2048 + 11 sigma) -- no count matrix, no scan kernels.
//   transpose_cast: W -> bf16x2-packed WTh[N][32]; also inits slab cursors
//   partition (256 blocks x 1024 thr, persistent): per-block LDS hist over
//     1563 buckets -> 1 global atomicAdd per (block,bucket) reserves a
//     frontier range (~8 edges = 32B => ~2x write amp max) -> re-read edges
//     (L2-hot) -> scatter packed (row&63)<<17|col into slabs
//   sort_gather (unchanged R5 consumer): per-bucket LDS counting sort +
//     half-wave-per-edge gather of bf16 WT columns, f32 accum.

#define OUTC 64
#define NF_MAX 2048
#define SLAB 2560          // per-bucket slab capacity (mean 2048, sigma 45)
#define CAP 2560           // gather LDS capacity == SLAB
#define PBLOCKS 256
#define PTHREADS 1024

__device__ inline unsigned f2bf(float x) {           // RNE f32 -> bf16 bits
    unsigned u = __float_as_uint(x);
    return (u + 0x7FFFu + ((u >> 16) & 1u)) >> 16;
}
__device__ inline float bf_lo(unsigned u) { return __uint_as_float(u << 16); }
__device__ inline float bf_hi(unsigned u) { return __uint_as_float(u & 0xFFFF0000u); }

// ---------------- A: transpose W[64][N] -> WTh[N][32] bf16x2; init cursors ----------------
__global__ __launch_bounds__(256) void transpose_cast(const float* __restrict__ W,
                                                      unsigned* __restrict__ WTh,
                                                      int* __restrict__ gcur,
                                                      int n, int NF) {
    // slab cursor init (grid is ~1563 blocks, covers NF with room to spare)
    int gi = blockIdx.x * 256 + threadIdx.x;
    if (gi < NF) gcur[gi] = gi * SLAB;

    __shared__ float tile[64][65];
    const int n0   = blockIdx.x * 64;
    const int lane = threadIdx.x & 63;
    const int wv   = threadIdx.x >> 6;
    #pragma unroll
    for (int k = 0; k < 16; ++k) {
        int o  = wv * 16 + k;
        int nn = n0 + lane;
        tile[o][lane] = (nn < n) ? W[(size_t)o * n + nn] : 0.f;
    }
    __syncthreads();
    const int u   = threadIdx.x & 31;
    const int nbs = threadIdx.x >> 5;
    #pragma unroll
    for (int k = 0; k < 8; ++k) {
        int nl = nbs + 8 * k;
        int nn = n0 + nl;
        if (nn < n)
            WTh[(size_t)nn * 32 + u] = f2bf(tile[2 * u][nl]) | (f2bf(tile[2 * u + 1][nl]) << 16);
    }
}

// ---------------- B: single-kernel partition into fixed slabs ----------------
__global__ __launch_bounds__(PTHREADS) void partition(const int* __restrict__ rows,
                                                      const int* __restrict__ cols,
                                                      int* __restrict__ gcur,
                                                      unsigned* __restrict__ packed,
                                                      int E, int NF) {
    __shared__ int h[NF_MAX];
    __shared__ int cur[NF_MAX];
    const int tid = threadIdx.x;
    for (int i = tid; i < NF; i += PTHREADS) h[i] = 0;
    __syncthreads();

    const int per  = (E + PBLOCKS - 1) / PBLOCKS;          // 12500
    const int base = blockIdx.x * per;
    const int lim  = min(E, base + per);
    if (base >= lim) return;
    const int alignEnd = base + ((lim - base) & ~3);

    // pass A: count into LDS hist
    for (int e = base + tid * 4; e + 3 < lim; e += PTHREADS * 4) {
        int4 r = *(const int4*)(rows + e);
        atomicAdd(&h[r.x >> 6], 1);
        atomicAdd(&h[r.y >> 6], 1);
        atomicAdd(&h[r.z >> 6], 1);
        atomicAdd(&h[r.w >> 6], 1);
    }
    for (int e = alignEnd + tid; e < lim; e += PTHREADS)
        atomicAdd(&h[rows[e] >> 6], 1);
    __syncthreads();

    // reserve a contiguous frontier range per bucket (1 global atomic each)
    for (int i = tid; i < NF; i += PTHREADS) {
        int c = h[i];
        cur[i] = c ? atomicAdd(&gcur[i], c) : 0;
    }
    __syncthreads();

    // pass B: re-read (L2-hot) and scatter packed (row&63)<<17 | col
    for (int e = base + tid * 4; e + 3 < lim; e += PTHREADS * 4) {
        int4 r  = *(const int4*)(rows + e);
        int4 cc = *(const int4*)(cols + e);
        int p0 = atomicAdd(&cur[r.x >> 6], 1);
        int p1 = atomicAdd(&cur[r.y >> 6], 1);
        int p2 = atomicAdd(&cur[r.z >> 6], 1);
        int p3 = atomicAdd(&cur[r.w >> 6], 1);
        packed[p0] = ((unsigned)(r.x & 63) << 17) | (unsigned)cc.x;
        packed[p1] = ((unsigned)(r.y & 63) << 17) | (unsigned)cc.y;
        packed[p2] = ((unsigned)(r.z & 63) << 17) | (unsigned)cc.z;
        packed[p3] = ((unsigned)(r.w & 63) << 17) | (unsigned)cc.w;
    }
    for (int e = alignEnd + tid; e < lim; e += PTHREADS) {
        int r = rows[e];
        int p = atomicAdd(&cur[r >> 6], 1);
        packed[p] = ((unsigned)(r & 63) << 17) | (unsigned)cols[e];
    }
}

// ---------------- C: fused per-bucket LDS counting sort + gather ----------------
__global__ __launch_bounds__(256) void sort_gather(const unsigned* __restrict__ WTh,
                                                   const unsigned* __restrict__ packed,
                                                   const int* __restrict__ gcur,
                                                   const float* __restrict__ bias,
                                                   float* __restrict__ out, int N) {
    __shared__ unsigned scol[CAP];            // 10 KB
    __shared__ int cnt[64], off0[64], tend[64], cur[64];
    __shared__ int ovf_n;
    __shared__ unsigned ovf[128];
    const int b    = blockIdx.x;
    const int tid  = threadIdx.x;
    const int lane = tid & 63;
    const int w    = tid >> 6;
    const int start = b * SLAB;
    int size = gcur[b] - start;
    if (size > SLAB) size = SLAB;             // paranoia (never at 11 sigma)
    if (tid < 64) cnt[tid] = 0;
    if (tid == 0) ovf_n = 0;
    __syncthreads();
    for (int e = tid; e < size; e += 256)
        atomicAdd(&cnt[packed[start + e] >> 17], 1);
    __syncthreads();
    int v = (tid < 64) ? cnt[tid] : 0;
    for (int off = 1; off < 64; off <<= 1) {
        int t = 0;
        if (tid < 64 && tid >= off) t = cnt[tid - off];
        __syncthreads();
        if (tid < 64 && tid >= off) cnt[tid] += t;
        __syncthreads();
    }
    if (tid < 64) { tend[tid] = cnt[tid]; off0[tid] = cnt[tid] - v; cur[tid] = cnt[tid] - v; }
    __syncthreads();
    for (int e = tid; e < size; e += 256) {
        unsigned u = packed[start + e];
        int p = atomicAdd(&cur[u >> 17], 1);
        if (p < CAP) scol[p] = u & 0x1FFFFu;
        else { int oi = atomicAdd(&ovf_n, 1); if (oi < 128) ovf[oi] = u; }
    }
    __syncthreads();
    const int hl   = lane & 31;
    const int half = lane >> 5;
    const float bx = bias[2 * hl];
    const float by = bias[2 * hl + 1];
    for (int r = w; r < 64; r += 4) {
        const int n = b * 64 + r;
        if (n >= N) break;
        int s = off0[r], t = tend[r];
        if (s > CAP) s = CAP;
        if (t > CAP) t = CAP;
        float ax = 0.f, ay = 0.f;
        int e = s + half;
        for (; e + 14 < t; e += 16) {
            unsigned c0 = scol[e + 0],  c1 = scol[e + 2],  c2 = scol[e + 4],  c3 = scol[e + 6];
            unsigned c4 = scol[e + 8],  c5 = scol[e + 10], c6 = scol[e + 12], c7 = scol[e + 14];
            unsigned u0 = WTh[(size_t)c0 * 32 + hl];
            unsigned u1 = WTh[(size_t)c1 * 32 + hl];
            unsigned u2 = WTh[(size_t)c2 * 32 + hl];
            unsigned u3 = WTh[(size_t)c3 * 32 + hl];
            unsigned u4 = WTh[(size_t)c4 * 32 + hl];
            unsigned u5 = WTh[(size_t)c5 * 32 + hl];
            unsigned u6 = WTh[(size_t)c6 * 32 + hl];
            unsigned u7 = WTh[(size_t)c7 * 32 + hl];
            ax += bf_lo(u0); ay += bf_hi(u0);
            ax += bf_lo(u1); ay += bf_hi(u1);
            ax += bf_lo(u2); ay += bf_hi(u2);
            ax += bf_lo(u3); ay += bf_hi(u3);
            ax += bf_lo(u4); ay += bf_hi(u4);
            ax += bf_lo(u5); ay += bf_hi(u5);
            ax += bf_lo(u6); ay += bf_hi(u6);
            ax += bf_lo(u7); ay += bf_hi(u7);
        }
        for (; e < t; e += 2) {
            unsigned u = WTh[(size_t)scol[e] * 32 + hl];
            ax += bf_lo(u); ay += bf_hi(u);
        }
        ax += __shfl_xor(ax, 32);
        ay += __shfl_xor(ay, 32);
        if (half == 0) {
            float2 o;
            o.x = ax + bx;
            o.y = ay + by;
            ((float2*)out)[(size_t)n * 32 + hl] = o;
        }
    }
    __syncthreads();
    int no = ovf_n;
    if (no > 0) {
        if (no > 128) no = 128;
        for (int i = w; i < no; i += 4) {
            unsigned u = ovf[i];
            int n = b * 64 + (int)(u >> 17);
            if (n < N && half == 0) {
                unsigned uu = WTh[(size_t)(u & 0x1FFFFu) * 32 + hl];
                atomicAdd(&out[(size_t)n * 64 + 2 * hl],     bf_lo(uu));
                atomicAdd(&out[(size_t)n * 64 + 2 * hl + 1], bf_hi(uu));
            }
        }
    }
}

extern "C" void kernel_launch(void* const* d_in, const int* in_sizes, int n_in,
                              void* d_out, int out_size, void* d_ws, size_t ws_size,
                              hipStream_t stream) {
    const int*   edges = (const int*)d_in[0];    // [2, E]: rows then cols
    const float* W     = (const float*)d_in[1];  // [64, N]
    const float* bias  = (const float*)d_in[2];  // [64]
    float*       out   = (float*)d_out;          // [N, 64]

    const int E  = in_sizes[0] / 2;
    const int N  = in_sizes[1] / OUTC;
    const int NF = (N + 63) / 64;                // 1563 fine buckets

    // workspace layout (~29 MB)
    char* ws = (char*)d_ws;
    size_t off = 0;
    unsigned* WTh = (unsigned*)(ws + off); off += (size_t)N * 32 * sizeof(unsigned);
    off = (off + 255) & ~(size_t)255;
    int* gcur = (int*)(ws + off);          off += (size_t)NF * sizeof(int);
    off = (off + 255) & ~(size_t)255;
    unsigned* packed = (unsigned*)(ws + off); off += (size_t)NF * SLAB * sizeof(unsigned);
    (void)ws_size;

    const int* rows = edges;
    const int* cols = edges + E;

    transpose_cast<<<(N + 63) / 64, 256, 0, stream>>>(W, WTh, gcur, N, NF);
    partition<<<PBLOCKS, PTHREADS, 0, stream>>>(rows, cols, gcur, packed, E, NF);
    sort_gather<<<NF, 256, 0, stream>>>(WTh, packed, gcur, bias, out, N);
}

// Round 8
// 180.563 us; speedup vs baseline: 1.4472x; 1.1612x over previous
//
#include <hip/hip_runtime.h>
#include <hip/hip_bf16.h>

// LINK forward: out[i, o] = b[o] + sum over edges (i -> j) of W[o, j]
// N=100000, OUT=64, E=3200000.
//
// R8: R7 showed transpose ~50us (scalar f32 loads) and partition WRITE amp
// 5.5x (slab lines evicted mid-fill: 400K open frontiers > L2). Changes:
//  - transpose_cast: float4 reads (16B/lane)
//  - partition: block-local LDS counting sort (12544 edges in 49KB LDS);
//    each (block,bucket) run written contiguously at one instant ->
//    ~1-2x write amp, streaming stores
//  - sort_gather: UNCHANGED from R7 (control)

#define OUTC 64
#define NF_MAX 2048
#define SLAB 2560          // per-bucket slab capacity (mean 2048, sigma 45)
#define CAP 2560
#define EPB 12544          // edges per partition block (grid = ceil(E/EPB))

__device__ inline unsigned f2bf(float x) {           // RNE f32 -> bf16 bits
    unsigned u = __float_as_uint(x);
    return (u + 0x7FFFu + ((u >> 16) & 1u)) >> 16;
}
__device__ inline float bf_lo(unsigned u) { return __uint_as_float(u << 16); }
__device__ inline float bf_hi(unsigned u) { return __uint_as_float(u & 0xFFFF0000u); }

// ---------------- A: transpose W[64][N] -> WTh[N][32] bf16x2; init cursors ----------------
__global__ __launch_bounds__(256) void transpose_cast(const float* __restrict__ W,
                                                      unsigned* __restrict__ WTh,
                                                      int* __restrict__ gcur,
                                                      int n, int NF) {
    int gi = blockIdx.x * 256 + threadIdx.x;
    if (gi < NF) gcur[gi] = gi * SLAB;

    __shared__ float tile[64][65];   // +1 pad: read side is column access
    const int n0 = blockIdx.x * 64;
    // vectorized load: 64 rows x 16 float4 = 1024 float4s, 4 per thread
    #pragma unroll
    for (int k = 0; k < 4; ++k) {
        int idx = threadIdx.x + k * 256;
        int o   = idx >> 4;          // 0..63
        int q   = idx & 15;          // float4 index within row
        int nn  = n0 + q * 4;
        if (nn + 3 < n) {
            float4 v = *(const float4*)(W + (size_t)o * n + nn);
            tile[o][q * 4 + 0] = v.x;
            tile[o][q * 4 + 1] = v.y;
            tile[o][q * 4 + 2] = v.z;
            tile[o][q * 4 + 3] = v.w;
        } else {
            for (int j = 0; j < 4; ++j)
                tile[o][q * 4 + j] = (nn + j < n) ? W[(size_t)o * n + nn + j] : 0.f;
        }
    }
    __syncthreads();
    const int u   = threadIdx.x & 31;
    const int nbs = threadIdx.x >> 5;
    #pragma unroll
    for (int k = 0; k < 8; ++k) {
        int nl = nbs + 8 * k;
        int nn = n0 + nl;
        if (nn < n)
            WTh[(size_t)nn * 32 + u] = f2bf(tile[2 * u][nl]) | (f2bf(tile[2 * u + 1][nl]) << 16);
    }
}

// ---------------- B: partition via block-local LDS counting sort ----------------
__global__ __launch_bounds__(1024) void partition(const int* __restrict__ rows,
                                                  const int* __restrict__ cols,
                                                  int* __restrict__ gcur,
                                                  unsigned* __restrict__ packed,
                                                  int E, int NF) {
    __shared__ unsigned lbuf[EPB];        // 49 KB: block-sorted packed edges
    __shared__ int cnt[NF_MAX];           // raw counts
    __shared__ int loff[NF_MAX + 1];      // block-local exclusive offsets
    __shared__ int lcur[NF_MAX];          // scatter cursors
    __shared__ int gbase[NF_MAX];         // reserved global bases
    __shared__ int partial[1024];         // scan partials
    const int tid  = threadIdx.x;
    const int base = blockIdx.x * EPB;
    const int lim  = min(E, base + EPB);
    const int nE   = lim - base;
    if (nE <= 0) return;

    for (int i = tid; i < NF_MAX; i += 1024) cnt[i] = 0;
    __syncthreads();

    // pass A: count (int4 reads; base is EPB-aligned, EPB%4==0)
    for (int e = base + tid * 4; e + 3 < lim; e += 4096) {
        int4 r = *(const int4*)(rows + e);
        atomicAdd(&cnt[r.x >> 6], 1);
        atomicAdd(&cnt[r.y >> 6], 1);
        atomicAdd(&cnt[r.z >> 6], 1);
        atomicAdd(&cnt[r.w >> 6], 1);
    }
    {   // scalar tail
        int tailStart = base + ((nE) & ~3);
        for (int e = tailStart + tid; e < lim; e += 1024)
            atomicAdd(&cnt[rows[e] >> 6], 1);
    }
    __syncthreads();

    // block-wide exclusive scan of 2048 counters (2 per thread)
    int v0 = cnt[2 * tid], v1 = cnt[2 * tid + 1];
    int s  = v0 + v1;
    partial[tid] = s;
    __syncthreads();
    for (int off = 1; off < 1024; off <<= 1) {
        int t = 0;
        if (tid >= off) t = partial[tid - off];
        __syncthreads();
        if (tid >= off) partial[tid] += t;
        __syncthreads();
    }
    int ex = partial[tid] - s;
    loff[2 * tid]     = ex;
    loff[2 * tid + 1] = ex + v0;
    lcur[2 * tid]     = ex;
    lcur[2 * tid + 1] = ex + v0;
    if (tid == 1023) loff[2048] = partial[1023];
    __syncthreads();

    // reserve global ranges (1 atomic per non-empty bucket)
    for (int b = tid; b < NF; b += 1024) {
        int c = cnt[b];
        gbase[b] = c ? atomicAdd(&gcur[b], c) : 0;
    }
    __syncthreads();

    // pass B: re-read (L2-hot) and scatter into LDS in bucket order
    for (int e = base + tid * 4; e + 3 < lim; e += 4096) {
        int4 r  = *(const int4*)(rows + e);
        int4 cc = *(const int4*)(cols + e);
        int p0 = atomicAdd(&lcur[r.x >> 6], 1);
        int p1 = atomicAdd(&lcur[r.y >> 6], 1);
        int p2 = atomicAdd(&lcur[r.z >> 6], 1);
        int p3 = atomicAdd(&lcur[r.w >> 6], 1);
        lbuf[p0] = ((unsigned)(r.x & 63) << 17) | (unsigned)cc.x;
        lbuf[p1] = ((unsigned)(r.y & 63) << 17) | (unsigned)cc.y;
        lbuf[p2] = ((unsigned)(r.z & 63) << 17) | (unsigned)cc.z;
        lbuf[p3] = ((unsigned)(r.w & 63) << 17) | (unsigned)cc.w;
    }
    {
        int tailStart = base + (nE & ~3);
        for (int e = tailStart + tid; e < lim; e += 1024) {
            int r = rows[e];
            int p = atomicAdd(&lcur[r >> 6], 1);
            lbuf[p] = ((unsigned)(r & 63) << 17) | (unsigned)cols[e];
        }
    }
    __syncthreads();

    // pass C: copy runs to global. Thread t handles a contiguous chunk of
    // lbuf; consecutive threads -> consecutive global addresses within runs.
    const int chunk = (nE + 1023) >> 10;
    int i0 = tid * chunk;
    int i1 = min(nE, i0 + chunk);
    if (i0 < i1) {
        // binary search: largest b with loff[b] <= i0
        int lo = 0, hi = NF;
        while (hi - lo > 1) {
            int mid = (lo + hi) >> 1;
            if (loff[mid] <= i0) lo = mid; else hi = mid;
        }
        int b = lo;
        for (int i = i0; i < i1; ++i) {
            while (i >= loff[b + 1]) ++b;
            packed[gbase[b] + (i - loff[b])] = lbuf[i];
        }
    }
}

// ---------------- C: fused per-bucket LDS counting sort + gather (unchanged) ----------------
__global__ __launch_bounds__(256) void sort_gather(const unsigned* __restrict__ WTh,
                                                   const unsigned* __restrict__ packed,
                                                   const int* __restrict__ gcur,
                                                   const float* __restrict__ bias,
                                                   float* __restrict__ out, int N) {
    __shared__ unsigned scol[CAP];            // 10 KB
    __shared__ int cnt[64], off0[64], tend[64], cur[64];
    __shared__ int ovf_n;
    __shared__ unsigned ovf[128];
    const int b    = blockIdx.x;
    const int tid  = threadIdx.x;
    const int lane = tid & 63;
    const int w    = tid >> 6;
    const int start = b * SLAB;
    int size = gcur[b] - start;
    if (size > SLAB) size = SLAB;
    if (tid < 64) cnt[tid] = 0;
    if (tid == 0) ovf_n = 0;
    __syncthreads();
    for (int e = tid; e < size; e += 256)
        atomicAdd(&cnt[packed[start + e] >> 17], 1);
    __syncthreads();
    int v = (tid < 64) ? cnt[tid] : 0;
    for (int off = 1; off < 64; off <<= 1) {
        int t = 0;
        if (tid < 64 && tid >= off) t = cnt[tid - off];
        __syncthreads();
        if (tid < 64 && tid >= off) cnt[tid] += t;
        __syncthreads();
    }
    if (tid < 64) { tend[tid] = cnt[tid]; off0[tid] = cnt[tid] - v; cur[tid] = cnt[tid] - v; }
    __syncthreads();
    for (int e = tid; e < size; e += 256) {
        unsigned u = packed[start + e];
        int p = atomicAdd(&cur[u >> 17], 1);
        if (p < CAP) scol[p] = u & 0x1FFFFu;
        else { int oi = atomicAdd(&ovf_n, 1); if (oi < 128) ovf[oi] = u; }
    }
    __syncthreads();
    const int hl   = lane & 31;
    const int half = lane >> 5;
    const float bx = bias[2 * hl];
    const float by = bias[2 * hl + 1];
    for (int r = w; r < 64; r += 4) {
        const int n = b * 64 + r;
        if (n >= N) break;
        int s = off0[r], t = tend[r];
        if (s > CAP) s = CAP;
        if (t > CAP) t = CAP;
        float ax = 0.f, ay = 0.f;
        int e = s + half;
        for (; e + 14 < t; e += 16) {
            unsigned c0 = scol[e + 0],  c1 = scol[e + 2],  c2 = scol[e + 4],  c3 = scol[e + 6];
            unsigned c4 = scol[e + 8],  c5 = scol[e + 10], c6 = scol[e + 12], c7 = scol[e + 14];
            unsigned u0 = WTh[(size_t)c0 * 32 + hl];
            unsigned u1 = WTh[(size_t)c1 * 32 + hl];
            unsigned u2 = WTh[(size_t)c2 * 32 + hl];
            unsigned u3 = WTh[(size_t)c3 * 32 + hl];
            unsigned u4 = WTh[(size_t)c4 * 32 + hl];
            unsigned u5 = WTh[(size_t)c5 * 32 + hl];
            unsigned u6 = WTh[(size_t)c6 * 32 + hl];
            unsigned u7 = WTh[(size_t)c7 * 32 + hl];
            ax += bf_lo(u0); ay += bf_hi(u0);
            ax += bf_lo(u1); ay += bf_hi(u1);
            ax += bf_lo(u2); ay += bf_hi(u2);
            ax += bf_lo(u3); ay += bf_hi(u3);
            ax += bf_lo(u4); ay += bf_hi(u4);
            ax += bf_lo(u5); ay += bf_hi(u5);
            ax += bf_lo(u6); ay += bf_hi(u6);
            ax += bf_lo(u7); ay += bf_hi(u7);
        }
        for (; e < t; e += 2) {
            unsigned u = WTh[(size_t)scol[e] * 32 + hl];
            ax += bf_lo(u); ay += bf_hi(u);
        }
        ax += __shfl_xor(ax, 32);
        ay += __shfl_xor(ay, 32);
        if (half == 0) {
            float2 o;
            o.x = ax + bx;
            o.y = ay + by;
            ((float2*)out)[(size_t)n * 32 + hl] = o;
        }
    }
    __syncthreads();
    int no = ovf_n;
    if (no > 0) {
        if (no > 128) no = 128;
        for (int i = w; i < no; i += 4) {
            unsigned u = ovf[i];
            int n = b * 64 + (int)(u >> 17);
            if (n < N && half == 0) {
                unsigned uu = WTh[(size_t)(u & 0x1FFFFu) * 32 + hl];
                atomicAdd(&out[(size_t)n * 64 + 2 * hl],     bf_lo(uu));
                atomicAdd(&out[(size_t)n * 64 + 2 * hl + 1], bf_hi(uu));
            }
        }
    }
}

extern "C" void kernel_launch(void* const* d_in, const int* in_sizes, int n_in,
                              void* d_out, int out_size, void* d_ws, size_t ws_size,
                              hipStream_t stream) {
    const int*   edges = (const int*)d_in[0];    // [2, E]: rows then cols
    const float* W     = (const float*)d_in[1];  // [64, N]
    const float* bias  = (const float*)d_in[2];  // [64]
    float*       out   = (float*)d_out;          // [N, 64]

    const int E  = in_sizes[0] / 2;
    const int N  = in_sizes[1] / OUTC;
    const int NF = (N + 63) / 64;                // 1563 fine buckets

    // workspace layout (~29 MB)
    char* ws = (char*)d_ws;
    size_t off = 0;
    unsigned* WTh = (unsigned*)(ws + off); off += (size_t)N * 32 * sizeof(unsigned);
    off = (off + 255) & ~(size_t)255;
    int* gcur = (int*)(ws + off);          off += (size_t)NF * sizeof(int);
    off = (off + 255) & ~(size_t)255;
    unsigned* packed = (unsigned*)(ws + off); off += (size_t)NF * SLAB * sizeof(unsigned);
    (void)ws_size;

    const int* rows = edges;
    const int* cols = edges + E;

    const int pblocks = (E + EPB - 1) / EPB;     // 256 for E=3.2M

    transpose_cast<<<(N + 63) / 64, 256, 0, stream>>>(W, WTh, gcur, N, NF);
    partition<<<pblocks, 1024, 0, stream>>>(rows, cols, gcur, packed, E, NF);
    sort_gather<<<NF, 256, 0, stream>>>(WTh, packed, gcur, bias, out, N);
}